// Round 14
// baseline (253.959 us; speedup 1.0000x reference)
//
#include <hip/hip_runtime.h>
#include <hip/hip_bf16.h>
#include <stdint.h>

#define T_TOK 2048
#define HDIM  1024
#define IDIM  768
#define NEXP  32
#define TOPK  4
#define NPAIR (T_TOK*TOPK)   // 8192
#define MTILE 256
#define MAXMT 64

typedef __attribute__((ext_vector_type(8))) short bf16x8;
typedef __attribute__((ext_vector_type(4))) float f32x4;

typedef __attribute__((address_space(1))) const unsigned int gu32;
typedef __attribute__((address_space(3))) unsigned int lu32;

__device__ __forceinline__ void gload_lds16(const void* g, void* l){
  __builtin_amdgcn_global_load_lds((gu32*)g, (lu32*)l, 16, 0, 0);
}

#define WAITV(n) asm volatile("s_waitcnt vmcnt(" #n ")" ::: "memory")
#define BAR()    do{ asm volatile("" ::: "memory"); __builtin_amdgcn_s_barrier(); \
                     __builtin_amdgcn_sched_barrier(0); }while(0)

__device__ __forceinline__ unsigned short f2bf(float f){
  union { float f; unsigned u; } v; v.f = f;
  unsigned r = (v.u + 0x7fffu + ((v.u >> 16) & 1u)) >> 16;  // RNE
  return (unsigned short)r;
}

__device__ __forceinline__ unsigned pack_bf2(float lo, float hi){
  __hip_bfloat162 h2 = __float22bfloat162_rn(float2{lo, hi});  // v_cvt_pk_bf16_f32
  union { __hip_bfloat162 h; unsigned u; } v; v.h = h2;
  return v.u;
}

__device__ __forceinline__ bf16x8 cvt8(f32x4 x1, f32x4 x2){
  uint4 uu; uu.x=pack_bf2(x1[0],x1[1]); uu.y=pack_bf2(x1[2],x1[3]);
  uu.z=pack_bf2(x2[0],x2[1]); uu.w=pack_bf2(x2[2],x2[3]);
  return *reinterpret_cast<bf16x8*>(&uu);
}

// ---------------- router (+ fused x->bf16) ----------------
__global__ __launch_bounds__(256) void k_router(const float* __restrict__ x,
                                                const float* __restrict__ gw,
                                                int* __restrict__ ei, float* __restrict__ wv,
                                                int* __restrict__ counts,
                                                ushort* __restrict__ xb){
  int wid  = threadIdx.x >> 6;
  int lane = threadIdx.x & 63;
  int t = blockIdx.x*4 + wid;
  float xv[16];
  #pragma unroll
  for (int i=0;i<16;i++) xv[i] = x[t*HDIM + i*64 + lane];
  float p[NEXP];
  #pragma unroll
  for (int e=0;e<NEXP;e++){
    const float* w = gw + e*HDIM;
    float a = 0.f;
    #pragma unroll
    for (int i=0;i<16;i++) a = fmaf(xv[i], w[i*64+lane], a);
    #pragma unroll
    for (int off=32; off>=1; off>>=1) a += __shfl_xor(a, off, 64);
    p[e] = a;
  }
  float m = p[0];
  #pragma unroll
  for (int e=1;e<NEXP;e++) m = fmaxf(m, p[e]);
  #pragma unroll
  for (int e=0;e<NEXP;e++) p[e] = __expf(p[e]-m);
  unsigned used = 0; int sel[TOPK]; float sw[TOPK]; float wsum = 0.f;
  #pragma unroll
  for (int k=0;k<TOPK;k++){
    float best = -1.f; int bi = 0;
    #pragma unroll
    for (int e=0;e<NEXP;e++){
      bool ok = (((used>>e)&1u)==0u) && (p[e] > best);
      best = ok ? p[e] : best; bi = ok ? e : bi;
    }
    used |= 1u<<bi; sel[k]=bi; sw[k]=best; wsum += best;
  }
  if (lane==0){
    float inv = 1.f/wsum;
    #pragma unroll
    for (int k=0;k<TOPK;k++){
      ei[t*TOPK+k] = sel[k];
      wv[t*TOPK+k] = sw[k]*inv;
      atomicAdd(&counts[sel[k]], 1);
    }
  }
  #pragma unroll
  for (int kq=0;kq<4;kq++){
    float4 v = *(const float4*)(x + (size_t)t*HDIM + (kq*64+lane)*4);
    ushort4 o; o.x=f2bf(v.x); o.y=f2bf(v.y); o.z=f2bf(v.z); o.w=f2bf(v.w);
    *(ushort4*)(xb + (size_t)t*HDIM + (kq*64+lane)*4) = o;
  }
}

// ---------------- offsets + m-tile worklist ----------------
__global__ void k_offsets(const int* __restrict__ counts, int* __restrict__ offsets,
                          int* __restrict__ mtE, int* __restrict__ mtM0,
                          int* __restrict__ nmt){
  if (threadIdx.x==0 && blockIdx.x==0){
    int s=0;
    for (int e=0;e<NEXP;e++){ offsets[e]=s; s+=counts[e]; }
    offsets[NEXP]=s;
    int nm=0;
    for (int e=0;e<NEXP;e++){
      int ne = counts[e];
      for (int m0=0; m0<ne && nm<MAXMT; m0+=MTILE){ mtE[nm]=e; mtM0[nm]=m0; nm++; }
    }
    nmt[0]=nm;
  }
}

__global__ __launch_bounds__(256) void k_scatter(const int* __restrict__ ei,
                                                 const int* __restrict__ offsets,
                                                 int* __restrict__ cursor,
                                                 int* __restrict__ slot_tk,
                                                 int* __restrict__ tk_slot){
  int g = blockIdx.x*256 + threadIdx.x;
  int e = ei[g];
  int pos = atomicAdd(&cursor[e], 1);
  int slot = offsets[e] + pos;
  slot_tk[slot] = g;
  tk_slot[g] = slot;
}

// ---------------- gate+up GEMM + SiLU ----------------
// Tile M=256 x 64 i-cols (both mats). K=1024, BK=32, 32 steps.
// A[2][256][32] bf16 + B[2][128][32] f32, BOTH via global_load_lds (src-swizzled),
// dbuf, per-wave counted vmcnt(4), raw barriers. 8 waves 4m x 2n (64x64).
__global__ __launch_bounds__(512,4) void k_gateup(const ushort* __restrict__ xb,
    const float* __restrict__ w1, const float* __restrict__ w3,
    const int* __restrict__ offsets, const int* __restrict__ slot_tk,
    const int* __restrict__ mtE, const int* __restrict__ mtM0, const int* __restrict__ nmt,
    ushort* __restrict__ act){
  const int NST = 32;
  int bi  = blockIdx.x;               // 768
  int s0  = bi >> 3;
  int mti = (s0/12)*8 + (bi&7);       // same tile -> same XCD
  int nt  = s0 % 12;
  if (mti >= nmt[0]) return;
  int e    = mtE[mti];
  int m0   = mtM0[mti];
  int off0 = offsets[e];
  int ne   = offsets[e+1]-off0;
  int ibase = nt*64;

  __shared__ ushort Als[2][256][32];   // bf16, chunk-swizzled content
  __shared__ float  Bls[2][128][32];   // f32: rows 0-63 w1, 64-127 w3; swizzled
  __shared__ int toks[MTILE];

  int tid = threadIdx.x, wid = tid>>6, lane = tid&63;
  if (tid < MTILE){
    int slot = off0 + m0 + tid;
    int fb = slot_tk[off0] >> 2;
    toks[tid] = (m0 + tid < ne) ? (slot_tk[slot] >> 2) : fb;
  }
  __syncthreads();

  // ---- DMA descriptors: 2 A-instrs + 2 B-instrs per wave per step ----
  const ushort* aS[2]; ushort* aD[2];
  #pragma unroll
  for (int si=0;si<2;si++){
    int r0 = wid*32 + si*16;
    int row = r0 + (lane>>2);
    int csrc = (lane&3) ^ ((row>>1)&3);
    aS[si] = xb + (size_t)toks[row]*HDIM + csrc*8;
    aD[si] = &Als[0][r0][0];
  }
  const float* bS[2]; float* bD[2];
  #pragma unroll
  for (int si=0;si<2;si++){
    int r0 = wid*16 + si*8;
    int row = r0 + (lane>>3);
    int ir  = ibase + (row & 63);
    int csrc = (lane&7) ^ (row&7);
    bS[si] = ((row < 64) ? w1 : w3) + (size_t)e*IDIM*HDIM + (size_t)ir*HDIM + csrc*4;
    bD[si] = &Bls[0][r0][0];
  }

  int wm = wid>>1, wn = wid&1, q = lane>>4;
  f32x4 accg[4][2], accu[4][2];
  #pragma unroll
  for (int m=0;m<4;m++)
    #pragma unroll
    for (int n=0;n<2;n++){ accg[m][n]=(f32x4){0,0,0,0}; accu[m][n]=(f32x4){0,0,0,0}; }

  auto stage = [&](int buf, int h){
    gload_lds16(aS[0] + h*32, aD[0] + buf*8192);
    gload_lds16(aS[1] + h*32, aD[1] + buf*8192);
    gload_lds16(bS[0] + h*32, bD[0] + buf*4096);
    gload_lds16(bS[1] + h*32, bD[1] + buf*4096);
  };
  auto compute = [&](int buf){
    const ushort* Ab = &Als[buf][0][0];
    const float*  Bb = &Bls[buf][0][0];
    bf16x8 af[4];
    #pragma unroll
    for (int m=0;m<4;m++){
      int row = wm*64 + m*16 + (lane&15);
      int pa = q ^ ((row>>1)&3);
      af[m] = *(const bf16x8*)(Ab + row*32 + pa*8);
    }
    #pragma unroll
    for (int nf=0;nf<2;nf++){
      int rG = wn*32 + nf*16 + (lane&15);         // w1 row; w3 row = rG+64 (same &7)
      int c1 = (2*q) ^ (rG&7);
      f32x4 g1 = *(const f32x4*)(Bb + rG*32 + c1*4);
      f32x4 g2 = *(const f32x4*)(Bb + rG*32 + (c1^1)*4);
      f32x4 u1 = *(const f32x4*)(Bb + (rG+64)*32 + c1*4);
      f32x4 u2 = *(const f32x4*)(Bb + (rG+64)*32 + (c1^1)*4);
      bf16x8 bg = cvt8(g1,g2), bu = cvt8(u1,u2);
      #pragma unroll
      for (int m=0;m<4;m++){
        accg[m][nf] = __builtin_amdgcn_mfma_f32_16x16x32_bf16(af[m], bg, accg[m][nf], 0,0,0);
        accu[m][nf] = __builtin_amdgcn_mfma_f32_16x16x32_bf16(af[m], bu, accu[m][nf], 0,0,0);
      }
    }
  };

  stage(0,0);
  for (int h=0; h<NST; ++h){
    if (h+1 < NST){ stage((h+1)&1, h+1); WAITV(4); }
    else          { WAITV(0); }
    BAR();
    compute(h&1);
    BAR();
  }

  int nval = ne - m0; if (nval > MTILE) nval = MTILE;
  #pragma unroll
  for (int m=0;m<4;m++)
    #pragma unroll
    for (int nf=0;nf<2;nf++)
      #pragma unroll
      for (int r=0;r<4;r++){
        int row = wm*64 + m*16 + q*4 + r;
        if (row < nval){
          float g = accg[m][nf][r], u = accu[m][nf][r];
          float sval = g / (1.f + __expf(-g)) * u;
          act[(size_t)(off0+m0+row)*IDIM + ibase + wn*32 + nf*16 + (lane&15)] = f2bf(sval);
        }
      }
}

// ---------------- down GEMM ----------------
// Tile M=256 x 128 h-cols. K=768, BK=32, 24 steps. Same DMA template.
__global__ __launch_bounds__(512,4) void k_down(const ushort* __restrict__ act,
    const float* __restrict__ w2, const int* __restrict__ offsets,
    const int* __restrict__ mtE, const int* __restrict__ mtM0, const int* __restrict__ nmt,
    float* __restrict__ pout){
  const int NST = 24;
  int bi  = blockIdx.x;               // 512
  int s0  = bi >> 3;
  int mti = (s0/8)*8 + (bi&7);
  int nt  = s0 % 8;
  if (mti >= nmt[0]) return;
  int e    = mtE[mti];
  int m0   = mtM0[mti];
  int off0 = offsets[e], ne = offsets[e+1]-off0;
  int hbase = nt*128;

  __shared__ ushort Als[2][256][32];
  __shared__ float  Bls[2][128][32];

  int tid = threadIdx.x, wid = tid>>6, lane = tid&63;

  const ushort* aS[2]; ushort* aD[2];
  #pragma unroll
  for (int si=0;si<2;si++){
    int r0 = wid*32 + si*16;
    int row = r0 + (lane>>2);
    int mr = m0 + row; mr = (mr < ne) ? mr : (ne-1);
    int csrc = (lane&3) ^ ((row>>1)&3);
    aS[si] = act + (size_t)(off0+mr)*IDIM + csrc*8;
    aD[si] = &Als[0][r0][0];
  }
  const float* bS[2]; float* bD[2];
  #pragma unroll
  for (int si=0;si<2;si++){
    int r0 = wid*16 + si*8;
    int row = r0 + (lane>>3);
    int csrc = (lane&7) ^ (row&7);
    bS[si] = w2 + (size_t)e*HDIM*IDIM + (size_t)(hbase+row)*IDIM + csrc*4;
    bD[si] = &Bls[0][r0][0];
  }

  int wm = wid>>1, wn = wid&1, q = lane>>4;
  f32x4 acc[4][4];
  #pragma unroll
  for (int m=0;m<4;m++)
    #pragma unroll
    for (int n=0;n<4;n++) acc[m][n]=(f32x4){0,0,0,0};

  auto stage = [&](int buf, int h){
    gload_lds16(aS[0] + h*32, aD[0] + buf*8192);
    gload_lds16(aS[1] + h*32, aD[1] + buf*8192);
    gload_lds16(bS[0] + h*32, bD[0] + buf*4096);
    gload_lds16(bS[1] + h*32, bD[1] + buf*4096);
  };
  auto compute = [&](int buf){
    const ushort* Ab = &Als[buf][0][0];
    const float*  Bb = &Bls[buf][0][0];
    bf16x8 af[4];
    #pragma unroll
    for (int m=0;m<4;m++){
      int row = wm*64 + m*16 + (lane&15);
      int pa = q ^ ((row>>1)&3);
      af[m] = *(const bf16x8*)(Ab + row*32 + pa*8);
    }
    #pragma unroll
    for (int nf=0;nf<4;nf++){
      int rB = wn*64 + nf*16 + (lane&15);
      int c1 = (2*q) ^ (rB&7);
      f32x4 x1 = *(const f32x4*)(Bb + rB*32 + c1*4);
      f32x4 x2 = *(const f32x4*)(Bb + rB*32 + (c1^1)*4);
      bf16x8 b = cvt8(x1,x2);
      #pragma unroll
      for (int m=0;m<4;m++)
        acc[m][nf] = __builtin_amdgcn_mfma_f32_16x16x32_bf16(af[m], b, acc[m][nf], 0,0,0);
    }
  };

  stage(0,0);
  for (int h=0; h<NST; ++h){
    if (h+1 < NST){ stage((h+1)&1, h+1); WAITV(4); }
    else          { WAITV(0); }
    BAR();
    compute(h&1);
    BAR();
  }

  int nval = ne - m0; if (nval > MTILE) nval = MTILE;
  #pragma unroll
  for (int m=0;m<4;m++)
    #pragma unroll
    for (int nf=0;nf<4;nf++)
      #pragma unroll
      for (int r=0;r<4;r++){
        int row = wm*64 + m*16 + q*4 + r;
        if (row < nval)
          pout[(size_t)(off0+m0+row)*HDIM + hbase + wn*64 + nf*16 + (lane&15)] = acc[m][nf][r];
      }
}

// ---------------- combine ----------------
__global__ __launch_bounds__(256) void k_combine(const float* __restrict__ pout,
    const int* __restrict__ tk_slot, const float* __restrict__ wv,
    float* __restrict__ out){
  int t = blockIdx.x;
  int c = threadIdx.x;
  float a0=0,a1=0,a2=0,a3=0;
  #pragma unroll
  for (int k=0;k<TOPK;k++){
    int slot = tk_slot[t*TOPK+k];
    float w  = wv[t*TOPK+k];
    float4 v = *(const float4*)(pout + (size_t)slot*HDIM + c*4);
    a0 = fmaf(w, v.x, a0); a1 = fmaf(w, v.y, a1);
    a2 = fmaf(w, v.z, a2); a3 = fmaf(w, v.w, a3);
  }
  float4 o; o.x=a0; o.y=a1; o.z=a2; o.w=a3;
  *(float4*)(out + (size_t)t*HDIM + c*4) = o;
}

extern "C" void kernel_launch(void* const* d_in, const int* in_sizes, int n_in,
                              void* d_out, int out_size, void* d_ws, size_t ws_size,
                              hipStream_t stream){
  const float* x  = (const float*)d_in[0];
  const float* gw = (const float*)d_in[1];
  const float* w1 = (const float*)d_in[2];
  const float* w3 = (const float*)d_in[3];
  const float* w2 = (const float*)d_in[4];
  float* out = (float*)d_out;

  char* ws = (char*)d_ws;
  size_t off = 0;
  ushort* xb   = (ushort*)(ws + off); off += (size_t)T_TOK*HDIM*2;
  ushort* act  = (ushort*)(ws + off); off += (size_t)NPAIR*IDIM*2;
  float*  pout = (float*) (ws + off); off += (size_t)NPAIR*HDIM*4;
  int* counts  = (int*)(ws + off); off += NEXP*4;
  int* cursor  = (int*)(ws + off); off += NEXP*4;
  int* offsets = (int*)(ws + off); off += (NEXP+1)*4;
  int* mtE     = (int*)(ws + off); off += MAXMT*4;
  int* mtM0    = (int*)(ws + off); off += MAXMT*4;
  int* nmt     = (int*)(ws + off); off += 4;
  off = (off + 255) & ~(size_t)255;
  int*   ei      = (int*)  (ws + off); off += (size_t)NPAIR*4;
  float* wvp     = (float*)(ws + off); off += (size_t)NPAIR*4;
  int*   slot_tk = (int*)  (ws + off); off += (size_t)NPAIR*4;
  int*   tk_slot = (int*)  (ws + off); off += (size_t)NPAIR*4;

  hipMemsetAsync(counts, 0, 2*NEXP*4, stream);

  k_router<<<T_TOK/4, 256, 0, stream>>>(x, gw, ei, wvp, counts, xb);
  k_offsets<<<1, 64, 0, stream>>>(counts, offsets, mtE, mtM0, nmt);
  k_scatter<<<NPAIR/256, 256, 0, stream>>>(ei, offsets, cursor, slot_tk, tk_slot);
  k_gateup<<<MAXMT*12, 512, 0, stream>>>(xb, w1, w3, offsets, slot_tk, mtE, mtM0, nmt, act);
  k_down<<<MAXMT*8, 512, 0, stream>>>(act, w2, offsets, mtE, mtM0, nmt, pout);
  k_combine<<<T_TOK, 256, 0, stream>>>(pout, tk_slot, wvp, out);
}